// Round 10
// baseline (2044.608 us; speedup 1.0000x reference)
//
#include <hip/hip_runtime.h>

typedef __attribute__((ext_vector_type(8))) short short8;
typedef __attribute__((ext_vector_type(4))) float f32x4;
typedef __attribute__((ext_vector_type(2))) float f32x2;

#define NPTS 8192
#define NCTR 2048
#define CANDCAP 1536
#define NPROD 8
#define NCONS 128  // 16 consumer blocks per batch x 4 waves x 32 centers = 2048

__device__ __forceinline__ short f2bf(float f) {
  unsigned u = __float_as_uint(f);
  u += 0x7fffu + ((u >> 16) & 1u);
  return (short)(u >> 16);
}

// ---- wave64 reductions via DPP (VALU pipe) ----
template <int CTRL, int RM>
__device__ __forceinline__ unsigned long long dppmax64(unsigned long long k) {
  int lo = (int)(unsigned)k;
  int hi = (int)(unsigned)(k >> 32);
  int plo = __builtin_amdgcn_update_dpp(lo, lo, CTRL, RM, 0xf, false);
  int phi = __builtin_amdgcn_update_dpp(hi, hi, CTRL, RM, 0xf, false);
  unsigned long long o = ((unsigned long long)(unsigned)phi << 32) | (unsigned)(unsigned)plo;
  return (o > k) ? o : k;
}
template <int CTRL, int RM>
__device__ __forceinline__ unsigned long long dppmin64(unsigned long long k) {
  int lo = (int)(unsigned)k;
  int hi = (int)(unsigned)(k >> 32);
  int plo = __builtin_amdgcn_update_dpp(lo, lo, CTRL, RM, 0xf, false);
  int phi = __builtin_amdgcn_update_dpp(hi, hi, CTRL, RM, 0xf, false);
  unsigned long long o = ((unsigned long long)(unsigned)phi << 32) | (unsigned)(unsigned)plo;
  return (o < k) ? o : k;
}
__device__ __forceinline__ unsigned long long wave_max64(unsigned long long k) {
  k = dppmax64<0xB1, 0xF>(k);
  k = dppmax64<0x4E, 0xF>(k);
  k = dppmax64<0x141, 0xF>(k);
  k = dppmax64<0x140, 0xF>(k);
  k = dppmax64<0x142, 0xA>(k);
  k = dppmax64<0x143, 0xC>(k);
  return k;
}
__device__ __forceinline__ unsigned long long wave_min64(unsigned long long k) {
  k = dppmin64<0xB1, 0xF>(k);
  k = dppmin64<0x4E, 0xF>(k);
  k = dppmin64<0x141, 0xF>(k);
  k = dppmin64<0x140, 0xF>(k);
  k = dppmin64<0x142, 0xA>(k);
  k = dppmin64<0x143, 0xC>(k);
  return k;
}
__device__ __forceinline__ unsigned long long wave_bcast63(unsigned long long k) {
  unsigned lo = (unsigned)__builtin_amdgcn_readlane((int)(unsigned)k, 63);
  unsigned hi = (unsigned)__builtin_amdgcn_readlane((int)(unsigned)(k >> 32), 63);
  return ((unsigned long long)hi << 32) | lo;
}
__device__ __forceinline__ unsigned long long umin64(unsigned long long a, unsigned long long b) {
  return a < b ? a : b;
}

// ---------------- MEGA: producer blocks (FPS) + consumer blocks (ballq+MLP) ----------------
// prog is padded: slot for batch b is prog[b*64] (256 B apart -> no line sharing).
template <bool PACKED>
__global__ __launch_bounds__(256) void mega_kernel(
    const float* __restrict__ xyz, const float* __restrict__ feat,
    const short* __restrict__ featb, const short* __restrict__ wfrag,
    const float* __restrict__ tvecg, unsigned* __restrict__ prog,
    float* __restrict__ newxyz, float* __restrict__ outf) {
#pragma clang fp contract(off)
  __shared__ float xs[NPTS], ys[NPTS], zs[NPTS];              // 96 KB (both paths)
  __shared__ unsigned long long cand[4][CANDCAP];             // 48 KB (consumer; reused as X/Y tiles)
  __shared__ int outidx[4][32];
  __shared__ unsigned long long wkeys[2][4];                  // producer
  const int t = threadIdx.x;
  const int lane = t & 63;
  const int wid = t >> 6;

  if (blockIdx.x < NPROD) {
    // ================= PRODUCER: exact R3 FPS + progress publication =================
    const int b = blockIdx.x;
    const float* xb = xyz + (size_t)b * NPTS * 3;
    for (int i = t; i < NPTS * 3; i += 256) {
      float v = xb[i];
      int p = i / 3;
      int c = i - p * 3;
      if (c == 0) xs[p] = v; else if (c == 1) ys[p] = v; else zs[p] = v;
    }
    __syncthreads();
    f32x2 X2[16], Y2[16], Z2[16];
    float MD[32];
#pragma unroll
    for (int j = 0; j < 16; ++j) {
      int p0 = t + ((2 * j) << 8);
      int p1 = t + ((2 * j + 1) << 8);
      X2[j] = (f32x2){xs[p0], xs[p1]};
      Y2[j] = (f32x2){ys[p0], ys[p1]};
      Z2[j] = (f32x2){zs[p0], zs[p1]};
      MD[2 * j] = 1e10f;
      MD[2 * j + 1] = 1e10f;
    }
    float px = xs[0], py = ys[0], pz = zs[0];
    if (t == 0) {
      size_t ob = (size_t)b * NCTR * 3;
      newxyz[ob] = px; newxyz[ob + 1] = py; newxyz[ob + 2] = pz;
    }
    for (int it = 1; it < NCTR; ++it) {
      const f32x2 px2 = (f32x2){px, px};
      const f32x2 py2 = (f32x2){py, py};
      const f32x2 pz2 = (f32x2){pz, pz};
#pragma unroll
      for (int j = 0; j < 16; ++j) {
        f32x2 dx = X2[j] - px2;
        f32x2 dy = Y2[j] - py2;
        f32x2 dz = Z2[j] - pz2;
        f32x2 q0 = dx * dx;
        f32x2 q1 = dy * dy;
        f32x2 q2 = dz * dz;
        f32x2 d = (q0 + q1) + q2;
        MD[2 * j] = fminf(MD[2 * j], d.x);
        MD[2 * j + 1] = fminf(MD[2 * j + 1], d.y);
      }
      float m[16];
#pragma unroll
      for (int j = 0; j < 16; ++j) m[j] = fmaxf(MD[2 * j], MD[2 * j + 1]);
#pragma unroll
      for (int j = 0; j < 8; ++j) m[j] = fmaxf(m[2 * j], m[2 * j + 1]);
#pragma unroll
      for (int j = 0; j < 4; ++j) m[j] = fmaxf(m[2 * j], m[2 * j + 1]);
      float bv = fmaxf(fmaxf(m[0], m[1]), fmaxf(m[2], m[3]));
      int bp = 0;
#pragma unroll
      for (int j = 31; j >= 0; --j)
        if (MD[j] == bv) bp = t + (j << 8);  // smallest point index on ties
      unsigned long long key =
          ((unsigned long long)__float_as_uint(bv) << 32) | (unsigned long long)(8191 - bp);
      key = wave_bcast63(wave_max64(key));
      if (lane == 0) wkeys[it & 1][wid] = key;
      __syncthreads();
      unsigned long long k0 = wkeys[it & 1][0];
      unsigned long long k1 = wkeys[it & 1][1];
      unsigned long long k2 = wkeys[it & 1][2];
      unsigned long long k3 = wkeys[it & 1][3];
      unsigned long long ka = k0 > k1 ? k0 : k1;
      unsigned long long kb = k2 > k3 ? k2 : k3;
      unsigned long long kg = ka > kb ? ka : kb;
      const int idxw = 8191 - (int)(kg & 0xffffffffull);
      px = xs[idxw]; py = ys[idxw]; pz = zs[idxw];
      if (t == 0) {
        size_t ob = ((size_t)b * NCTR + it) * 3;
        newxyz[ob] = px; newxyz[ob + 1] = py; newxyz[ob + 2] = pz;
        if (((it + 1) & 31) == 0)
          __hip_atomic_store(&prog[b * 64], (unsigned)(it + 1), __ATOMIC_RELEASE,
                             __HIP_MEMORY_SCOPE_AGENT);
      }
    }
  } else {
    // ================= CONSUMER: per-center ballq + MLP, progress-gated =================
    const int cons = blockIdx.x - NPROD;
    const int b = cons & 7;
    const int cb = cons >> 3;  // 0..15
    const float* xb = xyz + (size_t)b * NPTS * 3;
    for (int i = t; i < NPTS * 3; i += 256) {
      float v = xb[i];
      int p = i / 3;
      int c = i - p * 3;
      if (c == 0) xs[p] = v; else if (c == 1) ys[p] = v; else zs[p] = v;
    }
    __syncthreads();
    const int wv = cb * 4 + wid;  // 0..63 within batch
    const int ar = lane & 15;
    const int ah = lane >> 4;
    const short8* wf8 = (const short8*)wfrag;
    short* Xw = (short*)&cand[wid][0];     // 32 x 128 shorts (8 KB)
    short* Yw = (short*)&cand[wid][1024];  // 32 x 64 shorts (4 KB)
    for (int j = 0; j < 32; ++j) {
      const int s = wv + (j << 6);
      for (;;) {
        unsigned pr = __hip_atomic_load(&prog[b * 64], __ATOMIC_ACQUIRE, __HIP_MEMORY_SCOPE_AGENT);
        if (pr > (unsigned)s) break;
        __builtin_amdgcn_s_sleep(16);
      }
      const float* c3 = newxyz + ((size_t)b * NCTR + s) * 3;
      float cx = c3[0], cy = c3[1], cz = c3[2];
      float a2 = (cx * cx + cy * cy) + cz * cz;
      int base = 0;
      for (int p0 = 0; p0 < NPTS; p0 += 64) {
        int p = p0 + lane;
        float bx = xs[p], by = ys[p], bz = zs[p];
        float b2 = (bx * bx + by * by) + bz * bz;
        float ab = fmaf(cz, bz, fmaf(cy, by, cx * bx));
        float s2 = (a2 + b2) - 2.0f * ab;
        s2 = fmaxf(s2, 0.0f);
        float dist = sqrtf(s2);
        bool in = dist < 0.2f;
        unsigned long long mask = __ballot(in);
        if (in) {
          int pos = base + (int)__popcll(mask & ((1ull << lane) - 1ull));
          if (pos < CANDCAP)
            cand[wid][pos] = ((unsigned long long)__float_as_uint(dist) << 32) | (unsigned)p;
        }
        base += (int)__popcll(mask);
      }
      int m = base < CANDCAP ? base : CANDCAP;
      if (m <= 512) {
        unsigned long long r0 = ~0ull, r1 = ~0ull, r2 = ~0ull, r3 = ~0ull;
        unsigned long long r4 = ~0ull, r5 = ~0ull, r6 = ~0ull, r7 = ~0ull;
        if (lane < m) r0 = cand[wid][lane];
        if (lane + 64 < m) r1 = cand[wid][lane + 64];
        if (lane + 128 < m) r2 = cand[wid][lane + 128];
        if (lane + 192 < m) r3 = cand[wid][lane + 192];
        if (lane + 256 < m) r4 = cand[wid][lane + 256];
        if (lane + 320 < m) r5 = cand[wid][lane + 320];
        if (lane + 384 < m) r6 = cand[wid][lane + 384];
        if (lane + 448 < m) r7 = cand[wid][lane + 448];
        const int nsel = m < 32 ? m : 32;
        for (int tsel = 0; tsel < nsel; ++tsel) {
          unsigned long long ka = umin64(umin64(r0, r1), umin64(r2, r3));
          unsigned long long kb = umin64(umin64(r4, r5), umin64(r6, r7));
          unsigned long long r = wave_bcast63(wave_min64(umin64(ka, kb)));
          r0 = (r0 == r) ? ~0ull : r0;
          r1 = (r1 == r) ? ~0ull : r1;
          r2 = (r2 == r) ? ~0ull : r2;
          r3 = (r3 == r) ? ~0ull : r3;
          r4 = (r4 == r) ? ~0ull : r4;
          r5 = (r5 == r) ? ~0ull : r5;
          r6 = (r6 == r) ? ~0ull : r6;
          r7 = (r7 == r) ? ~0ull : r7;
          if (lane == 0) outidx[wid][tsel] = (int)(r & 0xffffffffull);
        }
        if (lane == 0)
          for (int tsel = nsel; tsel < 32; ++tsel) outidx[wid][tsel] = 0;
      } else {
        for (int tsel = 0; tsel < 32; ++tsel) {
          if (tsel < m) {
            unsigned long long kmin = ~0ull;
            int kslot = -1;
            for (int p = lane; p < m; p += 64) {
              unsigned long long k = cand[wid][p];
              if (k < kmin) { kmin = k; kslot = p; }
            }
            unsigned long long r = wave_bcast63(wave_min64(kmin));
            if (kmin == r && kslot >= 0) cand[wid][kslot] = ~0ull;
            if (lane == 0) outidx[wid][tsel] = (int)(r & 0xffffffffull);
          } else {
            if (lane == 0) outidx[wid][tsel] = 0;
          }
        }
      }
      // ---- MLP for center s (wave-local; cand region reused as X/Y tiles) ----
      {
        const int r = lane & 31;
        const int h = lane >> 5;
        const int n = outidx[wid][r];
        if (PACKED) {
          const short8* fb8 = (const short8*)(featb + (((size_t)b * NPTS + n) << 6));
#pragma unroll
          for (int c4 = 0; c4 < 4; ++c4) {
            short8 pk = fb8[h * 4 + c4];
            const int chunk = h * 4 + c4;
            *(short8*)&Xw[r * 128 + ((chunk ^ (r & 7)) << 3)] = pk;
          }
        } else {
          const f32x4* fr4 = (const f32x4*)(feat + (((size_t)b * NPTS + n) << 6));
#pragma unroll
          for (int c4 = 0; c4 < 4; ++c4) {
            f32x4 u = fr4[h * 8 + c4 * 2];
            f32x4 v2 = fr4[h * 8 + c4 * 2 + 1];
            short8 pk;
            pk[0] = f2bf(u[0]); pk[1] = f2bf(u[1]); pk[2] = f2bf(u[2]); pk[3] = f2bf(u[3]);
            pk[4] = f2bf(v2[0]); pk[5] = f2bf(v2[1]); pk[6] = f2bf(v2[2]); pk[7] = f2bf(v2[3]);
            const int chunk = h * 4 + c4;
            *(short8*)&Xw[r * 128 + ((chunk ^ (r & 7)) << 3)] = pk;
          }
        }
        if (h == 0) {
          const float* pn = xyz + ((size_t)b * NPTS + n) * 3;
          short8 pk = {0, 0, 0, 0, 0, 0, 0, 0};
          pk[0] = f2bf(pn[0] - cx);
          pk[1] = f2bf(pn[1] - cy);
          pk[2] = f2bf(pn[2] - cz);
          *(short8*)&Xw[r * 128 + ((8 ^ (r & 7)) << 3)] = pk;
          short8 z = {0, 0, 0, 0, 0, 0, 0, 0};
          *(short8*)&Xw[r * 128 + ((9 ^ (r & 7)) << 3)] = z;
          *(short8*)&Xw[r * 128 + ((10 ^ (r & 7)) << 3)] = z;
          *(short8*)&Xw[r * 128 + ((11 ^ (r & 7)) << 3)] = z;
        }
      }
      f32x4 acc[2][4];
      const f32x4 zf = {0.f, 0.f, 0.f, 0.f};
#pragma unroll
      for (int mt = 0; mt < 2; ++mt)
#pragma unroll
        for (int ct = 0; ct < 4; ++ct) acc[mt][ct] = zf;
#pragma unroll
      for (int kc = 0; kc < 3; ++kc) {
        const int csw = (((kc << 2) + ah) ^ (ar & 7)) << 3;
        short8 a0 = *(const short8*)&Xw[ar * 128 + csw];
        short8 a1 = *(const short8*)&Xw[(16 + ar) * 128 + csw];
#pragma unroll
        for (int ct = 0; ct < 4; ++ct) {
          short8 bf = wf8[(kc * 4 + ct) * 64 + lane];
          acc[0][ct] = __builtin_amdgcn_mfma_f32_16x16x32_bf16(a0, bf, acc[0][ct], 0, 0, 0);
          acc[1][ct] = __builtin_amdgcn_mfma_f32_16x16x32_bf16(a1, bf, acc[1][ct], 0, 0, 0);
        }
      }
#pragma unroll
      for (int mt = 0; mt < 2; ++mt)
#pragma unroll
        for (int ct = 0; ct < 4; ++ct) {
          const float tc = tvecg[ct * 16 + ar];
          const int col = ct * 16 + ar;
#pragma unroll
          for (int q = 0; q < 4; ++q) {
            const int orow = mt * 16 + ah * 4 + q;
            float y = fmaxf(acc[mt][ct][q] + tc, 0.f);
            Yw[orow * 64 + (((col >> 3) ^ (orow & 7)) << 3) + (col & 7)] = f2bf(y);
          }
        }
#pragma unroll
      for (int mt = 0; mt < 2; ++mt)
#pragma unroll
        for (int ct = 0; ct < 4; ++ct) acc[mt][ct] = zf;
#pragma unroll
      for (int kc = 0; kc < 2; ++kc) {
        const int csw = (((kc << 2) + ah) ^ (ar & 7)) << 3;
        short8 a0 = *(const short8*)&Yw[ar * 64 + csw];
        short8 a1 = *(const short8*)&Yw[(16 + ar) * 64 + csw];
#pragma unroll
        for (int ct = 0; ct < 4; ++ct) {
          short8 bf = wf8[768 + (kc * 4 + ct) * 64 + lane];
          acc[0][ct] = __builtin_amdgcn_mfma_f32_16x16x32_bf16(a0, bf, acc[0][ct], 0, 0, 0);
          acc[1][ct] = __builtin_amdgcn_mfma_f32_16x16x32_bf16(a1, bf, acc[1][ct], 0, 0, 0);
        }
      }
#pragma unroll
      for (int mt = 0; mt < 2; ++mt)
#pragma unroll
        for (int ct = 0; ct < 4; ++ct) {
          const float tc = tvecg[64 + ct * 16 + ar];
          const int col = ct * 16 + ar;
#pragma unroll
          for (int q = 0; q < 4; ++q) {
            const int orow = mt * 16 + ah * 4 + q;
            float y = fmaxf(acc[mt][ct][q] + tc, 0.f);
            Yw[orow * 64 + (((col >> 3) ^ (orow & 7)) << 3) + (col & 7)] = f2bf(y);
          }
        }
#pragma unroll
      for (int nh = 0; nh < 2; ++nh) {
#pragma unroll
        for (int mt = 0; mt < 2; ++mt)
#pragma unroll
          for (int ct = 0; ct < 4; ++ct) acc[mt][ct] = zf;
#pragma unroll
        for (int kc = 0; kc < 2; ++kc) {
          const int csw = (((kc << 2) + ah) ^ (ar & 7)) << 3;
          short8 a0 = *(const short8*)&Yw[ar * 64 + csw];
          short8 a1 = *(const short8*)&Yw[(16 + ar) * 64 + csw];
#pragma unroll
          for (int ct = 0; ct < 4; ++ct) {
            short8 bf = wf8[1280 + (kc * 8 + nh * 4 + ct) * 64 + lane];
            acc[0][ct] = __builtin_amdgcn_mfma_f32_16x16x32_bf16(a0, bf, acc[0][ct], 0, 0, 0);
            acc[1][ct] = __builtin_amdgcn_mfma_f32_16x16x32_bf16(a1, bf, acc[1][ct], 0, 0, 0);
          }
        }
        float vv[4];
#pragma unroll
        for (int ct = 0; ct < 4; ++ct) {
          float pmax = fmaxf(
              fmaxf(fmaxf(acc[0][ct][0], acc[0][ct][1]), fmaxf(acc[0][ct][2], acc[0][ct][3])),
              fmaxf(fmaxf(acc[1][ct][0], acc[1][ct][1]), fmaxf(acc[1][ct][2], acc[1][ct][3])));
          pmax = fmaxf(pmax, __shfl_xor(pmax, 16));
          pmax = fmaxf(pmax, __shfl_xor(pmax, 32));
          vv[ct] = fmaxf(pmax + tvecg[128 + nh * 64 + ct * 16 + ar], 0.f);
        }
        float vout = (ah == 0) ? vv[0] : (ah == 1) ? vv[1] : (ah == 2) ? vv[2] : vv[3];
        outf[(((size_t)b * NCTR + s) << 7) + nh * 64 + (ah << 4) + ar] = vout;
      }
    }
  }
}

// ---------------- feat -> bf16 pre-pack (coalesced; identical f2bf rounding) ----------------
__global__ __launch_bounds__(256) void pack_kernel(const float* __restrict__ feat,
                                                   short* __restrict__ featb) {
  const size_t i = (size_t)blockIdx.x * 256 + threadIdx.x;
  const f32x4* src = (const f32x4*)(feat + i * 8);
  f32x4 u = src[0];
  f32x4 v = src[1];
  short8 pk;
  pk[0] = f2bf(u[0]); pk[1] = f2bf(u[1]); pk[2] = f2bf(u[2]); pk[3] = f2bf(u[3]);
  pk[4] = f2bf(v[0]); pk[5] = f2bf(v[1]); pk[6] = f2bf(v[2]); pk[7] = f2bf(v[3]);
  *(short8*)(featb + i * 8) = pk;
}

// ---------------- Prep: fold BN into weights, lay out MFMA B-fragments ----------------
__global__ __launch_bounds__(256) void prep_kernel(
    const float* __restrict__ W0, const float* __restrict__ b0, const float* __restrict__ g0,
    const float* __restrict__ be0, const float* __restrict__ m0, const float* __restrict__ v0,
    const float* __restrict__ W1, const float* __restrict__ b1, const float* __restrict__ g1,
    const float* __restrict__ be1, const float* __restrict__ m1, const float* __restrict__ v1,
    const float* __restrict__ W2, const float* __restrict__ b2, const float* __restrict__ g2,
    const float* __restrict__ be2, const float* __restrict__ m2, const float* __restrict__ v2,
    short* __restrict__ wfrag, float* __restrict__ tvec) {
  const int tid = threadIdx.x;
  if (tid < 64) {
    float sc = g0[tid] / sqrtf(v0[tid] + 1e-5f);
    tvec[tid] = (b0[tid] - m0[tid]) * sc + be0[tid];
  } else if (tid < 128) {
    int o = tid - 64;
    float sc = g1[o] / sqrtf(v1[o] + 1e-5f);
    tvec[tid] = (b1[o] - m1[o]) * sc + be1[o];
  } else {
    int o = tid - 128;
    float sc = g2[o] / sqrtf(v2[o] + 1e-5f);
    tvec[tid] = (b2[o] - m2[o]) * sc + be2[o];
  }
  for (int idx = tid; idx < 18432; idx += 256) {
    const float *W, *g, *v;
    int rem, NT, L;
    if (idx < 6144)       { L = 0; rem = idx;         W = W0; g = g0; v = v0; NT = 4; }
    else if (idx < 10240) { L = 1; rem = idx - 6144;  W = W1; g = g1; v = v1; NT = 4; }
    else                  { L = 2; rem = idx - 10240; W = W2; g = g2; v = v2; NT = 8; }
    int f = rem >> 9;
    int lane = (rem >> 3) & 63;
    int e = rem & 7;
    int kc = f / NT, ct = f - kc * NT;
    int o = ct * 16 + (lane & 15);
    int k = kc * 32 + ((lane >> 4) << 3) + e;
    float val = 0.0f;
    if (L == 0) {
      if (k < 64) val = W[o * 67 + (k + 3)];
      else if (k < 67) val = W[o * 67 + (k - 64)];
    } else {
      if (k < 64) val = W[o * 64 + k];
    }
    float sc = g[o] / sqrtf(v[o] + 1e-5f);
    wfrag[idx] = f2bf(val * sc);
  }
}

extern "C" void kernel_launch(void* const* d_in, const int* in_sizes, int n_in,
                              void* d_out, int out_size, void* d_ws, size_t ws_size,
                              hipStream_t stream) {
  const float* xyz = (const float*)d_in[0];
  const float* feat = (const float*)d_in[1];
  const float* P[18];
  for (int i = 0; i < 18; ++i) P[i] = (const float*)d_in[2 + i];

  char* ws = (char*)d_ws;
  unsigned* prog = (unsigned*)ws;            // 8 slots x 256 B stride = 2048 B
  short* wfrag = (short*)(ws + 2048);        // 36,864 B
  float* tvec = (float*)(ws + 38912);        // 1,024 B
  short* featb = (short*)(ws + 40192);       // 8,388,608 B (optional)
  const bool packed = ws_size >= (40192ull + 8388608ull);

  float* newxyz = (float*)d_out;
  float* outf = (float*)d_out + 49152;

  hipMemsetAsync(prog, 0, 2048, stream);
  if (packed) pack_kernel<<<dim3(2048), dim3(256), 0, stream>>>(feat, featb);
  prep_kernel<<<dim3(1), dim3(256), 0, stream>>>(
      P[0], P[1], P[2], P[3], P[4], P[5],
      P[6], P[7], P[8], P[9], P[10], P[11],
      P[12], P[13], P[14], P[15], P[16], P[17],
      wfrag, tvec);
  if (packed)
    mega_kernel<true><<<dim3(NPROD + NCONS), dim3(256), 0, stream>>>(
        xyz, feat, featb, wfrag, tvec, prog, newxyz, outf);
  else
    mega_kernel<false><<<dim3(NPROD + NCONS), dim3(256), 0, stream>>>(
        xyz, feat, featb, wfrag, tvec, prog, newxyz, outf);
}

// Round 11
// 2030.494 us; speedup vs baseline: 1.0070x; 1.0070x over previous
//
#include <hip/hip_runtime.h>

typedef __attribute__((ext_vector_type(8))) short short8;
typedef __attribute__((ext_vector_type(4))) float f32x4;
typedef __attribute__((ext_vector_type(2))) float f32x2;

#define NPTS 8192
#define NCTR 2048
#define CANDCAP 1536
#define NPROD 8
#define NCONS 128  // 16 consumer blocks per batch x 4 waves x 32 centers = 2048

// smem overlay layout (bytes)
#define SM_XS 0
#define SM_YS 32768
#define SM_ZS 65536
#define SM_CAND 98304    // 4 waves x 1536 u64 = 49152 B
#define SM_OUTIDX 147456 // 4 x 32 int = 512 B
#define SM_WKEYS 147968  // 2 x 4 u64 = 64 B
#define SM_TOTAL 148032

__device__ __forceinline__ short f2bf(float f) {
  unsigned u = __float_as_uint(f);
  u += 0x7fffu + ((u >> 16) & 1u);
  return (short)(u >> 16);
}

// ---- wave64 reductions via DPP (VALU pipe) ----
template <int CTRL, int RM>
__device__ __forceinline__ unsigned long long dppmax64(unsigned long long k) {
  int lo = (int)(unsigned)k;
  int hi = (int)(unsigned)(k >> 32);
  int plo = __builtin_amdgcn_update_dpp(lo, lo, CTRL, RM, 0xf, false);
  int phi = __builtin_amdgcn_update_dpp(hi, hi, CTRL, RM, 0xf, false);
  unsigned long long o = ((unsigned long long)(unsigned)phi << 32) | (unsigned)(unsigned)plo;
  return (o > k) ? o : k;
}
template <int CTRL, int RM>
__device__ __forceinline__ unsigned long long dppmin64(unsigned long long k) {
  int lo = (int)(unsigned)k;
  int hi = (int)(unsigned)(k >> 32);
  int plo = __builtin_amdgcn_update_dpp(lo, lo, CTRL, RM, 0xf, false);
  int phi = __builtin_amdgcn_update_dpp(hi, hi, CTRL, RM, 0xf, false);
  unsigned long long o = ((unsigned long long)(unsigned)phi << 32) | (unsigned)(unsigned)plo;
  return (o < k) ? o : k;
}
__device__ __forceinline__ unsigned long long wave_max64(unsigned long long k) {
  k = dppmax64<0xB1, 0xF>(k);
  k = dppmax64<0x4E, 0xF>(k);
  k = dppmax64<0x141, 0xF>(k);
  k = dppmax64<0x140, 0xF>(k);
  k = dppmax64<0x142, 0xA>(k);
  k = dppmax64<0x143, 0xC>(k);
  return k;
}
__device__ __forceinline__ unsigned long long wave_min64(unsigned long long k) {
  k = dppmin64<0xB1, 0xF>(k);
  k = dppmin64<0x4E, 0xF>(k);
  k = dppmin64<0x141, 0xF>(k);
  k = dppmin64<0x140, 0xF>(k);
  k = dppmin64<0x142, 0xA>(k);
  k = dppmin64<0x143, 0xC>(k);
  return k;
}
__device__ __forceinline__ unsigned long long wave_bcast63(unsigned long long k) {
  unsigned lo = (unsigned)__builtin_amdgcn_readlane((int)(unsigned)k, 63);
  unsigned hi = (unsigned)__builtin_amdgcn_readlane((int)(unsigned)(k >> 32), 63);
  return ((unsigned long long)hi << 32) | lo;
}
__device__ __forceinline__ unsigned long long umin64(unsigned long long a, unsigned long long b) {
  return a < b ? a : b;
}

// ---------------- CONSUMER path: noinline so it cannot perturb producer codegen ----------------
template <bool PACKED>
__device__ __attribute__((noinline)) void consumer_path(
    char* smem, int cons, int t,
    const float* __restrict__ xyz, const float* __restrict__ feat,
    const short* __restrict__ featb, const short* __restrict__ wfrag,
    const float* __restrict__ tvecg, unsigned* __restrict__ prog,
    float* __restrict__ newxyz, float* __restrict__ outf) {
#pragma clang fp contract(off)
  float* xs = (float*)(smem + SM_XS);
  float* ys = (float*)(smem + SM_YS);
  float* zs = (float*)(smem + SM_ZS);
  unsigned long long* candb = (unsigned long long*)(smem + SM_CAND);
  int* outidxb = (int*)(smem + SM_OUTIDX);
  const int lane = t & 63;
  const int wid = t >> 6;
  unsigned long long* cand = candb + wid * CANDCAP;
  int* outidx = outidxb + wid * 32;
  const int b = cons & 7;
  const int cb = cons >> 3;  // 0..15
  const float* xb = xyz + (size_t)b * NPTS * 3;
  for (int i = t; i < NPTS * 3; i += 256) {
    float v = xb[i];
    int p = i / 3;
    int c = i - p * 3;
    if (c == 0) xs[p] = v; else if (c == 1) ys[p] = v; else zs[p] = v;
  }
  __syncthreads();
  const int wv = cb * 4 + wid;  // 0..63 within batch
  const int ar = lane & 15;
  const int ah = lane >> 4;
  const short8* wf8 = (const short8*)wfrag;
  short* Xw = (short*)cand;            // 32 x 128 shorts (8 KB)
  short* Yw = (short*)(cand + 1024);   // 32 x 64 shorts (4 KB)
  for (int j = 0; j < 32; ++j) {
    const int s = wv + (j << 6);
    for (;;) {
      unsigned pr = __hip_atomic_load(&prog[b * 64], __ATOMIC_ACQUIRE, __HIP_MEMORY_SCOPE_AGENT);
      if (pr > (unsigned)s) break;
      __builtin_amdgcn_s_sleep(16);
    }
    const float* c3 = newxyz + ((size_t)b * NCTR + s) * 3;
    float cx = c3[0], cy = c3[1], cz = c3[2];
    float a2 = (cx * cx + cy * cy) + cz * cz;
    int base = 0;
    for (int p0 = 0; p0 < NPTS; p0 += 64) {
      int p = p0 + lane;
      float bx = xs[p], by = ys[p], bz = zs[p];
      float b2 = (bx * bx + by * by) + bz * bz;
      float ab = fmaf(cz, bz, fmaf(cy, by, cx * bx));
      float s2 = (a2 + b2) - 2.0f * ab;
      s2 = fmaxf(s2, 0.0f);
      float dist = sqrtf(s2);
      bool in = dist < 0.2f;
      unsigned long long mask = __ballot(in);
      if (in) {
        int pos = base + (int)__popcll(mask & ((1ull << lane) - 1ull));
        if (pos < CANDCAP)
          cand[pos] = ((unsigned long long)__float_as_uint(dist) << 32) | (unsigned)p;
      }
      base += (int)__popcll(mask);
    }
    int m = base < CANDCAP ? base : CANDCAP;
    if (m <= 512) {
      unsigned long long r0 = ~0ull, r1 = ~0ull, r2 = ~0ull, r3 = ~0ull;
      unsigned long long r4 = ~0ull, r5 = ~0ull, r6 = ~0ull, r7 = ~0ull;
      if (lane < m) r0 = cand[lane];
      if (lane + 64 < m) r1 = cand[lane + 64];
      if (lane + 128 < m) r2 = cand[lane + 128];
      if (lane + 192 < m) r3 = cand[lane + 192];
      if (lane + 256 < m) r4 = cand[lane + 256];
      if (lane + 320 < m) r5 = cand[lane + 320];
      if (lane + 384 < m) r6 = cand[lane + 384];
      if (lane + 448 < m) r7 = cand[lane + 448];
      const int nsel = m < 32 ? m : 32;
      for (int tsel = 0; tsel < nsel; ++tsel) {
        unsigned long long ka = umin64(umin64(r0, r1), umin64(r2, r3));
        unsigned long long kb = umin64(umin64(r4, r5), umin64(r6, r7));
        unsigned long long r = wave_bcast63(wave_min64(umin64(ka, kb)));
        r0 = (r0 == r) ? ~0ull : r0;
        r1 = (r1 == r) ? ~0ull : r1;
        r2 = (r2 == r) ? ~0ull : r2;
        r3 = (r3 == r) ? ~0ull : r3;
        r4 = (r4 == r) ? ~0ull : r4;
        r5 = (r5 == r) ? ~0ull : r5;
        r6 = (r6 == r) ? ~0ull : r6;
        r7 = (r7 == r) ? ~0ull : r7;
        if (lane == 0) outidx[tsel] = (int)(r & 0xffffffffull);
      }
      if (lane == 0)
        for (int tsel = nsel; tsel < 32; ++tsel) outidx[tsel] = 0;
    } else {
      for (int tsel = 0; tsel < 32; ++tsel) {
        if (tsel < m) {
          unsigned long long kmin = ~0ull;
          int kslot = -1;
          for (int p = lane; p < m; p += 64) {
            unsigned long long k = cand[p];
            if (k < kmin) { kmin = k; kslot = p; }
          }
          unsigned long long r = wave_bcast63(wave_min64(kmin));
          if (kmin == r && kslot >= 0) cand[kslot] = ~0ull;
          if (lane == 0) outidx[tsel] = (int)(r & 0xffffffffull);
        } else {
          if (lane == 0) outidx[tsel] = 0;
        }
      }
    }
    // ---- MLP for center s (wave-local; cand region reused as X/Y tiles) ----
    {
      const int r = lane & 31;
      const int h = lane >> 5;
      const int n = outidx[r];
      if (PACKED) {
        const short8* fb8 = (const short8*)(featb + (((size_t)b * NPTS + n) << 6));
#pragma unroll
        for (int c4 = 0; c4 < 4; ++c4) {
          short8 pk = fb8[h * 4 + c4];
          const int chunk = h * 4 + c4;
          *(short8*)&Xw[r * 128 + ((chunk ^ (r & 7)) << 3)] = pk;
        }
      } else {
        const f32x4* fr4 = (const f32x4*)(feat + (((size_t)b * NPTS + n) << 6));
#pragma unroll
        for (int c4 = 0; c4 < 4; ++c4) {
          f32x4 u = fr4[h * 8 + c4 * 2];
          f32x4 v2 = fr4[h * 8 + c4 * 2 + 1];
          short8 pk;
          pk[0] = f2bf(u[0]); pk[1] = f2bf(u[1]); pk[2] = f2bf(u[2]); pk[3] = f2bf(u[3]);
          pk[4] = f2bf(v2[0]); pk[5] = f2bf(v2[1]); pk[6] = f2bf(v2[2]); pk[7] = f2bf(v2[3]);
          const int chunk = h * 4 + c4;
          *(short8*)&Xw[r * 128 + ((chunk ^ (r & 7)) << 3)] = pk;
        }
      }
      if (h == 0) {
        const float* pn = xyz + ((size_t)b * NPTS + n) * 3;
        short8 pk = {0, 0, 0, 0, 0, 0, 0, 0};
        pk[0] = f2bf(pn[0] - cx);
        pk[1] = f2bf(pn[1] - cy);
        pk[2] = f2bf(pn[2] - cz);
        *(short8*)&Xw[r * 128 + ((8 ^ (r & 7)) << 3)] = pk;
        short8 z = {0, 0, 0, 0, 0, 0, 0, 0};
        *(short8*)&Xw[r * 128 + ((9 ^ (r & 7)) << 3)] = z;
        *(short8*)&Xw[r * 128 + ((10 ^ (r & 7)) << 3)] = z;
        *(short8*)&Xw[r * 128 + ((11 ^ (r & 7)) << 3)] = z;
      }
    }
    f32x4 acc[2][4];
    const f32x4 zf = {0.f, 0.f, 0.f, 0.f};
#pragma unroll
    for (int mt = 0; mt < 2; ++mt)
#pragma unroll
      for (int ct = 0; ct < 4; ++ct) acc[mt][ct] = zf;
#pragma unroll
    for (int kc = 0; kc < 3; ++kc) {
      const int csw = (((kc << 2) + ah) ^ (ar & 7)) << 3;
      short8 a0 = *(const short8*)&Xw[ar * 128 + csw];
      short8 a1 = *(const short8*)&Xw[(16 + ar) * 128 + csw];
#pragma unroll
      for (int ct = 0; ct < 4; ++ct) {
        short8 bf = wf8[(kc * 4 + ct) * 64 + lane];
        acc[0][ct] = __builtin_amdgcn_mfma_f32_16x16x32_bf16(a0, bf, acc[0][ct], 0, 0, 0);
        acc[1][ct] = __builtin_amdgcn_mfma_f32_16x16x32_bf16(a1, bf, acc[1][ct], 0, 0, 0);
      }
    }
#pragma unroll
    for (int mt = 0; mt < 2; ++mt)
#pragma unroll
      for (int ct = 0; ct < 4; ++ct) {
        const float tc = tvecg[ct * 16 + ar];
        const int col = ct * 16 + ar;
#pragma unroll
        for (int q = 0; q < 4; ++q) {
          const int orow = mt * 16 + ah * 4 + q;
          float y = fmaxf(acc[mt][ct][q] + tc, 0.f);
          Yw[orow * 64 + (((col >> 3) ^ (orow & 7)) << 3) + (col & 7)] = f2bf(y);
        }
      }
#pragma unroll
    for (int mt = 0; mt < 2; ++mt)
#pragma unroll
      for (int ct = 0; ct < 4; ++ct) acc[mt][ct] = zf;
#pragma unroll
    for (int kc = 0; kc < 2; ++kc) {
      const int csw = (((kc << 2) + ah) ^ (ar & 7)) << 3;
      short8 a0 = *(const short8*)&Yw[ar * 64 + csw];
      short8 a1 = *(const short8*)&Yw[(16 + ar) * 64 + csw];
#pragma unroll
      for (int ct = 0; ct < 4; ++ct) {
        short8 bf = wf8[768 + (kc * 4 + ct) * 64 + lane];
        acc[0][ct] = __builtin_amdgcn_mfma_f32_16x16x32_bf16(a0, bf, acc[0][ct], 0, 0, 0);
        acc[1][ct] = __builtin_amdgcn_mfma_f32_16x16x32_bf16(a1, bf, acc[1][ct], 0, 0, 0);
      }
    }
#pragma unroll
    for (int mt = 0; mt < 2; ++mt)
#pragma unroll
      for (int ct = 0; ct < 4; ++ct) {
        const float tc = tvecg[64 + ct * 16 + ar];
        const int col = ct * 16 + ar;
#pragma unroll
        for (int q = 0; q < 4; ++q) {
          const int orow = mt * 16 + ah * 4 + q;
          float y = fmaxf(acc[mt][ct][q] + tc, 0.f);
          Yw[orow * 64 + (((col >> 3) ^ (orow & 7)) << 3) + (col & 7)] = f2bf(y);
        }
      }
#pragma unroll
    for (int nh = 0; nh < 2; ++nh) {
#pragma unroll
      for (int mt = 0; mt < 2; ++mt)
#pragma unroll
        for (int ct = 0; ct < 4; ++ct) acc[mt][ct] = zf;
#pragma unroll
      for (int kc = 0; kc < 2; ++kc) {
        const int csw = (((kc << 2) + ah) ^ (ar & 7)) << 3;
        short8 a0 = *(const short8*)&Yw[ar * 64 + csw];
        short8 a1 = *(const short8*)&Yw[(16 + ar) * 64 + csw];
#pragma unroll
        for (int ct = 0; ct < 4; ++ct) {
          short8 bf = wf8[1280 + (kc * 8 + nh * 4 + ct) * 64 + lane];
          acc[0][ct] = __builtin_amdgcn_mfma_f32_16x16x32_bf16(a0, bf, acc[0][ct], 0, 0, 0);
          acc[1][ct] = __builtin_amdgcn_mfma_f32_16x16x32_bf16(a1, bf, acc[1][ct], 0, 0, 0);
        }
      }
      float vv[4];
#pragma unroll
      for (int ct = 0; ct < 4; ++ct) {
        float pmax = fmaxf(
            fmaxf(fmaxf(acc[0][ct][0], acc[0][ct][1]), fmaxf(acc[0][ct][2], acc[0][ct][3])),
            fmaxf(fmaxf(acc[1][ct][0], acc[1][ct][1]), fmaxf(acc[1][ct][2], acc[1][ct][3])));
        pmax = fmaxf(pmax, __shfl_xor(pmax, 16));
        pmax = fmaxf(pmax, __shfl_xor(pmax, 32));
        vv[ct] = fmaxf(pmax + tvecg[128 + nh * 64 + ct * 16 + ar], 0.f);
      }
      float vout = (ah == 0) ? vv[0] : (ah == 1) ? vv[1] : (ah == 2) ? vv[2] : vv[3];
      outf[(((size_t)b * NCTR + s) << 7) + nh * 64 + (ah << 4) + ar] = vout;
    }
  }
}

// ---------------- MEGA: producer (inline, isolated codegen) + consumer (noinline) ----------------
template <bool PACKED>
__global__ __launch_bounds__(256) void mega_kernel(
    const float* __restrict__ xyz, const float* __restrict__ feat,
    const short* __restrict__ featb, const short* __restrict__ wfrag,
    const float* __restrict__ tvecg, unsigned* __restrict__ prog,
    float* __restrict__ newxyz, float* __restrict__ outf) {
#pragma clang fp contract(off)
  __shared__ __align__(16) char smem[SM_TOTAL];
  const int t = threadIdx.x;

  if (blockIdx.x >= NPROD) {
    consumer_path<PACKED>(smem, blockIdx.x - NPROD, t, xyz, feat, featb, wfrag, tvecg, prog,
                          newxyz, outf);
    return;
  }
  // ================= PRODUCER: exact R3 FPS + progress publication =================
  float* xs = (float*)(smem + SM_XS);
  float* ys = (float*)(smem + SM_YS);
  float* zs = (float*)(smem + SM_ZS);
  unsigned long long* wkeys = (unsigned long long*)(smem + SM_WKEYS);  // [2][4]
  const int lane = t & 63;
  const int wid = t >> 6;
  const int b = blockIdx.x;
  const float* xb = xyz + (size_t)b * NPTS * 3;
  for (int i = t; i < NPTS * 3; i += 256) {
    float v = xb[i];
    int p = i / 3;
    int c = i - p * 3;
    if (c == 0) xs[p] = v; else if (c == 1) ys[p] = v; else zs[p] = v;
  }
  __syncthreads();
  f32x2 X2[16], Y2[16], Z2[16];
  float MD[32];
#pragma unroll
  for (int j = 0; j < 16; ++j) {
    int p0 = t + ((2 * j) << 8);
    int p1 = t + ((2 * j + 1) << 8);
    X2[j] = (f32x2){xs[p0], xs[p1]};
    Y2[j] = (f32x2){ys[p0], ys[p1]};
    Z2[j] = (f32x2){zs[p0], zs[p1]};
    MD[2 * j] = 1e10f;
    MD[2 * j + 1] = 1e10f;
  }
  float px = xs[0], py = ys[0], pz = zs[0];
  if (t == 0) {
    size_t ob = (size_t)b * NCTR * 3;
    newxyz[ob] = px; newxyz[ob + 1] = py; newxyz[ob + 2] = pz;
  }
  for (int it = 1; it < NCTR; ++it) {
    const f32x2 px2 = (f32x2){px, px};
    const f32x2 py2 = (f32x2){py, py};
    const f32x2 pz2 = (f32x2){pz, pz};
#pragma unroll
    for (int j = 0; j < 16; ++j) {
      f32x2 dx = X2[j] - px2;
      f32x2 dy = Y2[j] - py2;
      f32x2 dz = Z2[j] - pz2;
      f32x2 q0 = dx * dx;
      f32x2 q1 = dy * dy;
      f32x2 q2 = dz * dz;
      f32x2 d = (q0 + q1) + q2;
      MD[2 * j] = fminf(MD[2 * j], d.x);
      MD[2 * j + 1] = fminf(MD[2 * j + 1], d.y);
    }
    float m[16];
#pragma unroll
    for (int j = 0; j < 16; ++j) m[j] = fmaxf(MD[2 * j], MD[2 * j + 1]);
#pragma unroll
    for (int j = 0; j < 8; ++j) m[j] = fmaxf(m[2 * j], m[2 * j + 1]);
#pragma unroll
    for (int j = 0; j < 4; ++j) m[j] = fmaxf(m[2 * j], m[2 * j + 1]);
    float bv = fmaxf(fmaxf(m[0], m[1]), fmaxf(m[2], m[3]));
    int bp = 0;
#pragma unroll
    for (int j = 31; j >= 0; --j)
      if (MD[j] == bv) bp = t + (j << 8);  // smallest point index on ties
    unsigned long long key =
        ((unsigned long long)__float_as_uint(bv) << 32) | (unsigned long long)(8191 - bp);
    key = wave_bcast63(wave_max64(key));
    if (lane == 0) wkeys[(it & 1) * 4 + wid] = key;
    __syncthreads();
    unsigned long long k0 = wkeys[(it & 1) * 4 + 0];
    unsigned long long k1 = wkeys[(it & 1) * 4 + 1];
    unsigned long long k2 = wkeys[(it & 1) * 4 + 2];
    unsigned long long k3 = wkeys[(it & 1) * 4 + 3];
    unsigned long long ka = k0 > k1 ? k0 : k1;
    unsigned long long kb = k2 > k3 ? k2 : k3;
    unsigned long long kg = ka > kb ? ka : kb;
    const int idxw = 8191 - (int)(kg & 0xffffffffull);
    px = xs[idxw]; py = ys[idxw]; pz = zs[idxw];
    if (t == 0) {
      size_t ob = ((size_t)b * NCTR + it) * 3;
      newxyz[ob] = px; newxyz[ob + 1] = py; newxyz[ob + 2] = pz;
      if (((it + 1) & 31) == 0)
        __hip_atomic_store(&prog[b * 64], (unsigned)(it + 1), __ATOMIC_RELEASE,
                           __HIP_MEMORY_SCOPE_AGENT);
    }
  }
}

// ---------------- feat -> bf16 pre-pack (coalesced; identical f2bf rounding) ----------------
__global__ __launch_bounds__(256) void pack_kernel(const float* __restrict__ feat,
                                                   short* __restrict__ featb) {
  const size_t i = (size_t)blockIdx.x * 256 + threadIdx.x;
  const f32x4* src = (const f32x4*)(feat + i * 8);
  f32x4 u = src[0];
  f32x4 v = src[1];
  short8 pk;
  pk[0] = f2bf(u[0]); pk[1] = f2bf(u[1]); pk[2] = f2bf(u[2]); pk[3] = f2bf(u[3]);
  pk[4] = f2bf(v[0]); pk[5] = f2bf(v[1]); pk[6] = f2bf(v[2]); pk[7] = f2bf(v[3]);
  *(short8*)(featb + i * 8) = pk;
}

// ---------------- Prep: fold BN into weights, lay out MFMA B-fragments ----------------
__global__ __launch_bounds__(256) void prep_kernel(
    const float* __restrict__ W0, const float* __restrict__ b0, const float* __restrict__ g0,
    const float* __restrict__ be0, const float* __restrict__ m0, const float* __restrict__ v0,
    const float* __restrict__ W1, const float* __restrict__ b1, const float* __restrict__ g1,
    const float* __restrict__ be1, const float* __restrict__ m1, const float* __restrict__ v1,
    const float* __restrict__ W2, const float* __restrict__ b2, const float* __restrict__ g2,
    const float* __restrict__ be2, const float* __restrict__ m2, const float* __restrict__ v2,
    short* __restrict__ wfrag, float* __restrict__ tvec) {
  const int tid = threadIdx.x;
  if (tid < 64) {
    float sc = g0[tid] / sqrtf(v0[tid] + 1e-5f);
    tvec[tid] = (b0[tid] - m0[tid]) * sc + be0[tid];
  } else if (tid < 128) {
    int o = tid - 64;
    float sc = g1[o] / sqrtf(v1[o] + 1e-5f);
    tvec[tid] = (b1[o] - m1[o]) * sc + be1[o];
  } else {
    int o = tid - 128;
    float sc = g2[o] / sqrtf(v2[o] + 1e-5f);
    tvec[tid] = (b2[o] - m2[o]) * sc + be2[o];
  }
  for (int idx = tid; idx < 18432; idx += 256) {
    const float *W, *g, *v;
    int rem, NT, L;
    if (idx < 6144)       { L = 0; rem = idx;         W = W0; g = g0; v = v0; NT = 4; }
    else if (idx < 10240) { L = 1; rem = idx - 6144;  W = W1; g = g1; v = v1; NT = 4; }
    else                  { L = 2; rem = idx - 10240; W = W2; g = g2; v = v2; NT = 8; }
    int f = rem >> 9;
    int lane = (rem >> 3) & 63;
    int e = rem & 7;
    int kc = f / NT, ct = f - kc * NT;
    int o = ct * 16 + (lane & 15);
    int k = kc * 32 + ((lane >> 4) << 3) + e;
    float val = 0.0f;
    if (L == 0) {
      if (k < 64) val = W[o * 67 + (k + 3)];
      else if (k < 67) val = W[o * 67 + (k - 64)];
    } else {
      if (k < 64) val = W[o * 64 + k];
    }
    float sc = g[o] / sqrtf(v[o] + 1e-5f);
    wfrag[idx] = f2bf(val * sc);
  }
}

extern "C" void kernel_launch(void* const* d_in, const int* in_sizes, int n_in,
                              void* d_out, int out_size, void* d_ws, size_t ws_size,
                              hipStream_t stream) {
  const float* xyz = (const float*)d_in[0];
  const float* feat = (const float*)d_in[1];
  const float* P[18];
  for (int i = 0; i < 18; ++i) P[i] = (const float*)d_in[2 + i];

  char* ws = (char*)d_ws;
  unsigned* prog = (unsigned*)ws;            // 8 slots x 256 B stride = 2048 B
  short* wfrag = (short*)(ws + 2048);        // 36,864 B
  float* tvec = (float*)(ws + 38912);        // 1,024 B
  short* featb = (short*)(ws + 40192);       // 8,388,608 B (optional)
  const bool packed = ws_size >= (40192ull + 8388608ull);

  float* newxyz = (float*)d_out;
  float* outf = (float*)d_out + 49152;

  hipMemsetAsync(prog, 0, 2048, stream);
  if (packed) pack_kernel<<<dim3(2048), dim3(256), 0, stream>>>(feat, featb);
  prep_kernel<<<dim3(1), dim3(256), 0, stream>>>(
      P[0], P[1], P[2], P[3], P[4], P[5],
      P[6], P[7], P[8], P[9], P[10], P[11],
      P[12], P[13], P[14], P[15], P[16], P[17],
      wfrag, tvec);
  if (packed)
    mega_kernel<true><<<dim3(NPROD + NCONS), dim3(256), 0, stream>>>(
        xyz, feat, featb, wfrag, tvec, prog, newxyz, outf);
  else
    mega_kernel<false><<<dim3(NPROD + NCONS), dim3(256), 0, stream>>>(
        xyz, feat, featb, wfrag, tvec, prog, newxyz, outf);
}